// Round 8
// baseline (111.018 us; speedup 1.0000x reference)
//
#include <hip/hip_runtime.h>
#include <hip/hip_bf16.h>

#define B_N   8192
#define DIN   512
#define DH    512
#define NACT  18
#define NTASK 16
#define BM    64
#define GBN   128
#define BK    64
#define PJ    20      // pbuf row stride (floats)
#define NSLOT 640     // 8 residues x 80 queue slots

typedef __attribute__((ext_vector_type(8))) short  short8v;
typedef __attribute__((ext_vector_type(8))) unsigned short ushort8v;
typedef __attribute__((ext_vector_type(4))) float  float4v;
typedef __attribute__((ext_vector_type(2))) float  float2v;

typedef const __attribute__((address_space(1))) void* gas_ptr;
typedef __attribute__((address_space(3))) void* las_ptr;

__device__ __forceinline__ unsigned short bfbits(float f) {
  union { float f; unsigned int u; } c; c.f = f;
  unsigned int u = c.u;
  u += 0x7fffu + ((u >> 16) & 1u);   // RNE
  return (unsigned short)(u >> 16);
}

// ============================================================ hist (1 block)
__global__ __launch_bounds__(1024) void k_hist(
    const int* __restrict__ task_id, int* __restrict__ tbl,
    int* __restrict__ rowidx, int* __restrict__ tile_cnt) {
  __shared__ int c4[4][NTASK], cur4[4][NTASK];
  int tid = threadIdx.x;
  if (tid < 64) ((int*)c4)[tid] = 0;
  for (int i = tid; i < NTASK * 128; i += 1024) tile_cnt[i] = 0;
  __syncthreads();
  for (int i = tid; i < B_N; i += 1024) atomicAdd(&c4[i >> 11][task_id[i]], 1);
  __syncthreads();
  if (tid == 0) {
    int acc = 0;
#pragma unroll
    for (int t = 0; t < NTASK; ++t) {
      int c = c4[0][t] + c4[1][t] + c4[2][t] + c4[3][t];
      tbl[t] = c; tbl[16 + t] = acc;
      int o = acc;
#pragma unroll
      for (int q = 0; q < 4; ++q) { cur4[q][t] = o; o += c4[q][t]; }
      acc += c;
    }
  }
  __syncthreads();
  for (int i = tid; i < B_N; i += 1024) {
    int t = task_id[i];
    rowidx[atomicAdd(&cur4[i >> 11][t], 1)] = i;
  }
}

// ============================================================ pack kernel
// Fragment-major packing for mfma_f32_16x16x32_bf16 (verified in round 7):
//   chunk (16B/lane x 64 lanes = 1 KB) = one (fragment, kstep); lane holds
//   n/j = frag*16+(lane&15), k = kstep*32+(lane>>4)*8 .. +8.
// b < 1024 : W1 [t][k][n] -> W1F (task t packs on residue t&7 -> XCD-local)
// b >= 1024: W2 [t][k][18] -> W2F
__global__ __launch_bounds__(256) void k_pack(
    const float* __restrict__ W1, const float* __restrict__ W2,
    short* __restrict__ W1F, short* __restrict__ W2F) {
  __shared__ __align__(16) short ldsA[64][72];
  __shared__ float ldsB[64 * 19];
  int b = blockIdx.x, tid = threadIdx.x;

  if (b < 1024) {
    int r = b & 7, q = b >> 3;
    int t = r + 8 * (q >> 6);
    int sub = q & 63;
    int kb = sub >> 3, nb = sub & 7;
    int kr = tid >> 2, c16 = (tid & 3) << 4;
    const float* src = W1 + ((size_t)t * DIN + (size_t)(kb * 64 + kr)) * DH + nb * 64 + c16;
#pragma unroll
    for (int p = 0; p < 4; ++p) {
      float4v v = *(const float4v*)(src + p * 4);
#pragma unroll
      for (int i = 0; i < 4; ++i) ldsA[c16 + p * 4 + i][kr] = (short)bfbits(v[i]);
    }
    __syncthreads();
#pragma unroll
    for (int it = 0; it < 2; ++it) {
      int idx = it * 256 + tid;
      int nf = idx >> 7, ksl = (idx >> 6) & 1, lane = idx & 63;
      int n_l = nf * 16 + (lane & 15);
      int k_l = ksl * 32 + (lane >> 4) * 8;
      ushort8v v = *(ushort8v*)&ldsA[n_l][k_l];
      size_t fid = ((size_t)t * 32 + nb * 4 + nf) * 16 + kb * 2 + ksl;
      *(ushort8v*)(W1F + (fid * 64 + lane) * 8) = v;
    }
  } else {
    int t = b - 1024;
    for (int kb = 0; kb < 8; ++kb) {
      __syncthreads();
      for (int i = tid; i < 64 * NACT; i += 256) {
        int kk = i / NACT, j = i - kk * NACT;
        ldsB[kk * 19 + j] = W2[((size_t)t * DIN + kb * 64 + kk) * NACT + j];
      }
      __syncthreads();
      int ksl = tid >> 7, jf = (tid >> 6) & 1, lane = tid & 63;
      int j = jf * 16 + (lane & 15);
      int k_l = ksl * 32 + (lane >> 4) * 8;
      ushort8v pk;
#pragma unroll
      for (int i = 0; i < 8; ++i) {
        float v = (j < NACT) ? ldsB[(k_l + i) * 19 + j] : 0.0f;
        pk[i] = (j < NACT) ? bfbits(v) : (unsigned short)0;
      }
      size_t fid = ((size_t)t * 2 + jf) * 16 + kb * 2 + ksl;
      *(ushort8v*)(W2F + (fid * 64 + lane) * 8) = pk;
    }
  }
}

// ============================================================ fused grouped GEMM
// 64x128 tiles, counted-vmcnt 2-phase pipeline, fragment-major B, reg-staged A.
__global__ __launch_bounds__(256, 2) void k_gemm1(
    const float* __restrict__ x, const float* __restrict__ bias1,
    const short* __restrict__ W1F, const short* __restrict__ W2F,
    const float* __restrict__ bias2, const int* __restrict__ action,
    const int* __restrict__ tbl, const int* __restrict__ rowidx,
    int* __restrict__ tile_cnt, float* __restrict__ pbuf,
    float* __restrict__ out) {
  __shared__ __align__(16) short sA[2][BM * 72];    // 2 x 9 KB (padded bf16)
  __shared__ __align__(16) short sB[2][GBN * BK];   // 2 x 16 KB fragment-major
  __shared__ __align__(16) short sH[BM * GBN];      // 16 KB, chunk-XOR swz
  __shared__ __align__(16) short sW2[8 * 1024 / 2]; // 8 KB: 8 fragment chunks
  __shared__ int s_rows[64];
  __shared__ int s_last;
  int tid = threadIdx.x, lane = tid & 63, wave = tid >> 6;

  // ---- decode (verified round 5): residue b&7 serves tasks {r, r+8}
  int b = blockIdx.x;
  int t = -1, rel = 0;
  if (b < NSLOT) {
    int r = b & 7, q = b >> 3;
    int n0t = (tbl[r] + 63) >> 6, n1t = (tbl[r + 8] + 63) >> 6;
    if (q < 4 * n0t) { t = r; rel = q; }
    else if (q < 4 * (n0t + n1t)) { t = r + 8; rel = q - 4 * n0t; }
    else return;
  } else {
    int j = b - NSLOT;
    for (int r = 0; r < 8; ++r) {
      int n0t = (tbl[r] + 63) >> 6, n1t = (tbl[r + 8] + 63) >> 6;
      int P = 4 * (n0t + n1t);
      int S = (P > 80) ? (P - 80) : 0;
      if (j < S) {
        int q = 80 + j;
        if (q < 4 * n0t) { t = r; rel = q; }
        else { t = r + 8; rel = q - 4 * n0t; }
        break;
      }
      j -= S;
    }
    if (t < 0) return;
  }
  int itile = rel >> 2, cs = rel & 3;
  int cnt_t = tbl[t], off_t = tbl[16 + t];
  int row0 = off_t + itile * 64;
  int mcnt = cnt_t - itile * 64; if (mcnt > 64) mcnt = 64;
  int n0 = cs * GBN;
  int wm = wave >> 1, wn = wave & 1;

  if (tid < 64) {
    int idx = row0 + tid;
    if (idx > B_N - 1) idx = B_N - 1;
    s_rows[tid] = rowidx[idx];
  }
  __syncthreads();

  // ---- staging setup
  int arow = tid >> 2, akc = (tid & 3) << 4;       // A: 4 thr/row, 16 k each
  const float* xrow = x + (size_t)s_rows[arow] * DIN + akc;
  // B: fragment chunks f0 = cs*8 .. +8, 16 chunks/step; c = it*4+wave (wave-uniform base)
  const short* w1f = W1F + (((size_t)t * 32 + cs * 8) * 16) * 512;  // *64 lanes *8 shorts

  float4v La[4];
#define LOAD_A(k0e) { _Pragma("unroll") for (int j_ = 0; j_ < 4; ++j_) \
    La[j_] = *(const float4v*)(xrow + (k0e) + j_ * 4); }
#define WRITE_A(buf) { ushort8v p0, p1;                                   \
    _Pragma("unroll") for (int i_ = 0; i_ < 4; ++i_) {                    \
      p0[i_] = bfbits(La[0][i_]); p0[4 + i_] = bfbits(La[1][i_]);         \
      p1[i_] = bfbits(La[2][i_]); p1[4 + i_] = bfbits(La[3][i_]); }       \
    *(ushort8v*)&sA[buf][arow * 72 + akc] = p0;                           \
    *(ushort8v*)&sA[buf][arow * 72 + akc + 8] = p1; }
  // B chunks for K-step s: fid_local = f*16 + s*2 + ksl, f=c>>1, ksl=c&1
#define STAGE_B(buf, s_)                                                     \
  _Pragma("unroll") for (int it = 0; it < 4; ++it) {                         \
    int c_ = it * 4 + wave;                                                  \
    size_t fl_ = (size_t)((c_ >> 1) * 16 + (s_) * 2 + (c_ & 1));             \
    __builtin_amdgcn_global_load_lds(                                        \
        (gas_ptr)(const void*)(w1f + fl_ * 512 + lane * 8),                  \
        (las_ptr)(void*)(&sB[buf][(c_ * 64 + lane) * 8]), 16, 0, 0);         \
  }

  // ---- prologue: W2 chunks (8) + B step0 (4) + A step0 (4 flat)
  {
    const short* w2f = W2F + ((size_t)t * 2 * 16) * 512;
#pragma unroll
    for (int it = 0; it < 2; ++it) {
      int d = it * 4 + wave;                       // jf = d>>2, ksr = d&3
      size_t fl = (size_t)((d >> 2) * 16 + cs * 4 + (d & 3));
      __builtin_amdgcn_global_load_lds(
          (gas_ptr)(const void*)(w2f + fl * 512 + lane * 8),
          (las_ptr)(void*)(&sW2[(d * 64 + lane) * 8]), 16, 0, 0);
    }
  }
  STAGE_B(0, 0)
  LOAD_A(0)
  asm volatile("s_waitcnt vmcnt(0)" ::: "memory");
  WRITE_A(0)
  asm volatile("s_waitcnt lgkmcnt(0)" ::: "memory");
  __builtin_amdgcn_s_barrier();

  float4v acc[2][4];
#pragma unroll
  for (int i = 0; i < 2; ++i)
#pragma unroll
    for (int j = 0; j < 4; ++j) acc[i][j] = (float4v)0.0f;

  for (int step = 0; step < 8; ++step) {
    int p = step & 1;
    if (step < 7) {
      LOAD_A((step + 1) * BK)          // 4 flat vmem
      STAGE_B(p ^ 1, step + 1)         // 4 global_load_lds
      asm volatile("s_waitcnt vmcnt(8)" ::: "memory");   // current tile landed
    } else {
      asm volatile("s_waitcnt vmcnt(0)" ::: "memory");
    }
    __builtin_amdgcn_s_barrier();
#pragma unroll
    for (int ks = 0; ks < 2; ++ks) {
      short8v a[2], bfr[4];
#pragma unroll
      for (int fm = 0; fm < 2; ++fm) {
        int r = wm * 32 + fm * 16 + (lane & 15);
        int c = ks * 4 + (lane >> 4);
        a[fm] = *(const short8v*)&sA[p][r * 72 + c * 8];
      }
#pragma unroll
      for (int fn = 0; fn < 4; ++fn) {
        // fragment f = wn*4+fn, chunk c = f*2+ksl ... reads contiguous 16B/lane
        int c = (wn * 4 + fn) * 2 + ks;
        bfr[fn] = *(const short8v*)&sB[p][(c * 64 + (lane & 15) + ((lane >> 4) << 4)) * 8];
      }
#pragma unroll
      for (int fm = 0; fm < 2; ++fm)
#pragma unroll
        for (int fn = 0; fn < 4; ++fn)
          acc[fm][fn] = __builtin_amdgcn_mfma_f32_16x16x32_bf16(a[fm], bfr[fn], acc[fm][fn], 0, 0, 0);
    }
    if (step < 7) {
      asm volatile("s_waitcnt vmcnt(4)" ::: "memory");   // A regs ready
      WRITE_A(p ^ 1)
    }
    asm volatile("s_waitcnt lgkmcnt(0)" ::: "memory");
    __builtin_amdgcn_s_barrier();
  }

  // ---- epilogue-1: +bias, relu, bf16 -> sH [m][n] chunk-swizzled (verified)
  float bias[4];
#pragma unroll
  for (int fn = 0; fn < 4; ++fn)
    bias[fn] = bias1[t * DH + n0 + wn * 64 + fn * 16 + (lane & 15)];
#pragma unroll
  for (int fn = 0; fn < 4; ++fn) {
    int n = wn * 64 + fn * 16 + (lane & 15);
#pragma unroll
    for (int fm = 0; fm < 2; ++fm) {
#pragma unroll
      for (int r = 0; r < 4; ++r) {
        int m = wm * 32 + fm * 16 + ((lane >> 4) << 2) + r;
        float v = fmaxf(acc[fm][fn][r] + bias[fn], 0.0f);
        *(short*)((char*)sH + m * 256 + (((n >> 3) ^ (m & 7)) << 4) + ((n & 7) << 1)) =
            (short)bfbits(v);
      }
    }
  }
  __syncthreads();

  // ---- partial GEMM2: this block's 128-n slice == 128-k slice of layer 2
  float4v acc2[2];
  acc2[0] = (float4v)0.0f; acc2[1] = (float4v)0.0f;
#pragma unroll
  for (int ks = 0; ks < 4; ++ks) {
    int mrow = wave * 16 + (lane & 15);
    int ca = (ks * 4 + (lane >> 4)) ^ (mrow & 7);
    short8v af = *(const short8v*)((char*)sH + mrow * 256 + (ca << 4));
#pragma unroll
    for (int fn = 0; fn < 2; ++fn) {
      int d = fn * 4 + ks;     // jf = fn, ksr = ks
      short8v bf = *(const short8v*)&sW2[(d * 64 + (lane & 15) + ((lane >> 4) << 4)) * 8];
      acc2[fn] = __builtin_amdgcn_mfma_f32_16x16x32_bf16(af, bf, acc2[fn], 0, 0, 0);
    }
  }
#pragma unroll
  for (int fn = 0; fn < 2; ++fn) {
#pragma unroll
    for (int r = 0; r < 4; ++r) {
      int m = wave * 16 + ((lane >> 4) << 2) + r;
      int j = fn * 16 + (lane & 15);
      if (m < mcnt && j < PJ)
        pbuf[((size_t)cs * B_N + row0 + m) * PJ + j] = acc2[fn][r];
    }
  }

  // ---- completion counter: last of the 4 cs-blocks reduces + softmax (verified R6)
  __threadfence();
  __syncthreads();
  if (tid == 0) {
    int key = (t << 7) | itile;
    s_last = (atomicAdd(&tile_cnt[key], 1) == 3) ? 1 : 0;
  }
  __syncthreads();
  if (s_last) {
    __threadfence();
    if (tid < mcnt) {
      int m = tid, orig = s_rows[m];
      int act = action[orig];
      float lg[NACT];
#pragma unroll
      for (int j = 0; j < NACT; ++j) {
        float v = bias2[t * NACT + j];
#pragma unroll
        for (int c = 0; c < 4; ++c)
          v += pbuf[((size_t)c * B_N + row0 + m) * PJ + j];
        lg[j] = v;
      }
      float mx = lg[0];
#pragma unroll
      for (int j = 1; j < NACT; ++j) mx = fmaxf(mx, lg[j]);
      float s1 = 0.0f, s2 = 0.0f, la = 0.0f;
#pragma unroll
      for (int j = 0; j < NACT; ++j) {
        float e = __expf(lg[j] - mx);
        s1 += e; s2 += e * lg[j];
        la = (j == act) ? lg[j] : la;
      }
      float logZ = __logf(s1);
      float2v o;
      o[0] = la - mx - logZ;
      o[1] = (mx + logZ) - s2 / s1;
      *(float2v*)(out + (size_t)orig * 2) = o;
    }
  }
#undef LOAD_A
#undef WRITE_A
#undef STAGE_B
}

// ----------------------------------------------------------------------------
extern "C" void kernel_launch(void* const* d_in, const int* in_sizes, int n_in,
                              void* d_out, int out_size, void* d_ws, size_t ws_size,
                              hipStream_t stream) {
  const float* x       = (const float*)d_in[0];
  const int*   task_id = (const int*)d_in[1];
  const int*   action  = (const int*)d_in[2];
  const float* W1      = (const float*)d_in[3];
  const float* b1      = (const float*)d_in[4];
  const float* W2      = (const float*)d_in[5];
  const float* b2      = (const float*)d_in[6];
  float* out = (float*)d_out;

  char* ws = (char*)d_ws;
  int* tbl      = (int*)ws;                // 32 ints
  int* rowidx   = (int*)(ws + 4096);       // 8192 ints -> ends 36864
  int* tile_cnt = (int*)(ws + 36864);      // 2048 ints -> ends 45056
  size_t off = 45056;
  short* W1F = (short*)(ws + off);  off += (size_t)NTASK * 32 * 16 * 64 * 16;  // 8.39 MB
  short* W2F = (short*)(ws + off);  off += (size_t)NTASK * 2 * 16 * 64 * 16;   // 0.52 MB
  float* pbuf = (float*)(ws + off);                                            // 2.62 MB

  k_hist<<<1, 1024, 0, stream>>>(task_id, tbl, rowidx, tile_cnt);
  k_pack<<<1040, 256, 0, stream>>>(W1, W2, W1F, W2F);
  k_gemm1<<<NSLOT + 576, 256, 0, stream>>>(x, b1, W1F, W2F, b2, action,
                                           tbl, rowidx, tile_cnt, pbuf, out);
}

// Round 9
// 43.067 us; speedup vs baseline: 2.5778x; 2.5778x over previous
//
#include <hip/hip_runtime.h>
#include <hip/hip_bf16.h>

#define B_N   8192
#define DIN   512
#define DH    512
#define NACT  18
#define NTASK 16
#define BM    64
#define GBN   128
#define BK    64
#define PJ    20      // pbuf row stride (floats)
#define NSLOT 640     // 8 residues x 80 queue slots

typedef __attribute__((ext_vector_type(8))) short  short8v;
typedef __attribute__((ext_vector_type(8))) unsigned short ushort8v;
typedef __attribute__((ext_vector_type(4))) float  float4v;
typedef __attribute__((ext_vector_type(2))) float  float2v;

typedef const __attribute__((address_space(1))) void* gas_ptr;
typedef __attribute__((address_space(3))) void* las_ptr;

__device__ __forceinline__ unsigned short f2bf(float f) {
  union { float f; unsigned int u; } c; c.f = f;
  unsigned int u = c.u;
  u += 0x7fffu + ((u >> 16) & 1u);   // RNE
  return (unsigned short)(u >> 16);
}

// ============================================================ prep kernel
// block 0          : histogram + 16-entry prefix + parallel scatter
// blocks 1..1024   : W1 [t][k][n] f32 -> W1T [t][n][k] bf16
//                    (XCD-aligned: tiles of task t written by blocks with bx%8==t&7,
//                     matching the gemm reader residue -> W1T stays XCD-L2-local)
// blocks 1025..1152: W2 [t][k][18] f32 -> W2T [t][32pad][512] bf16
__global__ __launch_bounds__(256) void k_prep(
    const float* __restrict__ W1, const float* __restrict__ W2,
    const int* __restrict__ task_id,
    short* __restrict__ W1T, short* __restrict__ W2T,
    int* __restrict__ tbl, int* __restrict__ rowidx) {
  __shared__ __align__(16) short ldsA[64][72];
  __shared__ float ldsB[64 * 19];
  __shared__ int s_cnt[NTASK], s_cur[NTASK];
  int bx = blockIdx.x, tid = threadIdx.x;

  if (bx == 0) {
    if (tid < NTASK) s_cnt[tid] = 0;
    __syncthreads();
    for (int i = tid; i < B_N; i += 256) atomicAdd(&s_cnt[task_id[i]], 1);
    __syncthreads();
    if (tid == 0) {                       // 16 iterations only
      int acc = 0;
#pragma unroll
      for (int t = 0; t < NTASK; ++t) {
        int c = s_cnt[t];
        tbl[t] = c; tbl[16 + t] = acc; s_cur[t] = acc;
        acc += c;
      }
    }
    __syncthreads();
    for (int i = tid; i < B_N; i += 256) {
      int t = task_id[i];
      rowidx[atomicAdd(&s_cur[t], 1)] = i;
    }
  } else if (bx <= 1024) {
    // residue-aligned decode: r = bx&7; q enumerates this residue's 128 tiles
    int r = bx & 7;
    int q = ((bx - r) >> 3) - (r == 0 ? 1 : 0);   // 0..127
    int t = r + ((q >> 6) << 3);                  // tasks {r, r+8}
    int sub = q & 63;
    int kb = sub >> 3, nb = sub & 7;
    int kr = tid >> 2, c16 = (tid & 3) << 4;
    const float* src = W1 + ((size_t)t * DIN + (size_t)(kb * 64 + kr)) * DH + nb * 64 + c16;
#pragma unroll
    for (int p = 0; p < 4; ++p) {
      float4v v = *(const float4v*)(src + p * 4);
#pragma unroll
      for (int i = 0; i < 4; ++i) ldsA[c16 + p * 4 + i][kr] = (short)f2bf(v[i]);
    }
    __syncthreads();
    int n = tid >> 2, k16 = (tid & 3) << 4;
    short* dst = W1T + ((size_t)t * DH + nb * 64 + n) * DIN + kb * 64 + k16;
    *(ushort8v*)dst       = *(ushort8v*)&ldsA[n][k16];
    *(ushort8v*)(dst + 8) = *(ushort8v*)&ldsA[n][k16 + 8];
  } else {
    int u = bx - 1025;
    int t = u >> 3, k0 = (u & 7) * 64;
    for (int i = tid; i < 64 * NACT; i += 256) {
      int kk = i / NACT, j = i - kk * NACT;
      ldsB[kk * 19 + j] = W2[((size_t)t * DIN + k0 + kk) * NACT + j];
    }
    __syncthreads();
    for (int o = tid; o < 32 * 64; o += 256) {
      int j = o >> 6, kk = o & 63;
      float val = (j < NACT) ? ldsB[kk * 19 + j] : 0.0f;
      W2T[((size_t)t * 32 + j) * DIN + k0 + kk] = (short)f2bf(val);
    }
  }
}

// ============================================================ grouped GEMM1 + partial GEMM2
// R5-proven structure; LDS trimmed to ~51.5 KB (sH/sW2 alias sB) -> 3 blocks/CU.
__global__ __launch_bounds__(256, 3) void k_gemm1(
    const float* __restrict__ x, const float* __restrict__ bias1,
    const short* __restrict__ W1T, const short* __restrict__ W2Tg,
    const int* __restrict__ tbl, const int* __restrict__ rowidx,
    float* __restrict__ pbuf) {
  __shared__ __align__(16) short sA[2][BM * 72];    // 2 x 9 KB (padded, reg-staged)
  __shared__ __align__(16) short sB[2][GBN * BK];   // 2 x 16 KB (gload_lds, XOR-swz)
  short* sH  = sB[0];   // 16 KB, used only after the K-loop
  short* sW2 = sB[1];   // 8 KB,  used only after the K-loop
  __shared__ int s_rows[64];
  int tid = threadIdx.x, lane = tid & 63, wave = tid >> 6;

  // ---- decode (verified R5): residue b&7 serves tasks {r, r+8}
  int b = blockIdx.x;
  int t = -1, rel = 0;
  if (b < NSLOT) {
    int r = b & 7, q = b >> 3;
    int n0t = (tbl[r] + 63) >> 6, n1t = (tbl[r + 8] + 63) >> 6;
    if (q < 4 * n0t) { t = r; rel = q; }
    else if (q < 4 * (n0t + n1t)) { t = r + 8; rel = q - 4 * n0t; }
    else return;
  } else {
    int j = b - NSLOT;
    for (int r = 0; r < 8; ++r) {
      int n0t = (tbl[r] + 63) >> 6, n1t = (tbl[r + 8] + 63) >> 6;
      int P = 4 * (n0t + n1t);
      int S = (P > 80) ? (P - 80) : 0;
      if (j < S) {
        int q = 80 + j;
        if (q < 4 * n0t) { t = r; rel = q; }
        else { t = r + 8; rel = q - 4 * n0t; }
        break;
      }
      j -= S;
    }
    if (t < 0) return;
  }
  int itile = rel >> 2, cs = rel & 3;
  int cnt_t = tbl[t], off_t = tbl[16 + t];
  int row0 = off_t + itile * 64;
  int mcnt = cnt_t - itile * 64; if (mcnt > 64) mcnt = 64;
  int n0 = cs * GBN;
  int wm = wave >> 1, wn = wave & 1;

  if (tid < 64) {
    int idx = row0 + tid;
    if (idx > B_N - 1) idx = B_N - 1;
    s_rows[tid] = rowidx[idx];
  }
  __syncthreads();

  // ---- staging setup
  int arow = tid >> 2, akc = (tid & 3) << 4;       // A: 4 thr/row, 16 k each
  const float* xrow = x + (size_t)s_rows[arow] * DIN + akc;
  const short* Bbase = W1T + ((size_t)t * DH + n0) * DIN;

#define STAGE_B(buf, k0e)                                                    \
  _Pragma("unroll") for (int it = 0; it < 4; ++it) {                         \
    int ch = it * 256 + tid; int row = ch >> 3, cc = ch & 7;                 \
    int sc = cc ^ (row & 7);                                                 \
    __builtin_amdgcn_global_load_lds(                                        \
        (gas_ptr)(const void*)(Bbase + (size_t)row * DIN + (k0e) + sc * 8),  \
        (las_ptr)(void*)(&sB[buf][ch * 8]), 16, 0, 0);                       \
  }
#define STAGE_A(buf, k0e) {                                                  \
    const float* xs_ = xrow + (k0e);                                         \
    float4v v0 = *(const float4v*)xs_;                                       \
    float4v v1 = *(const float4v*)(xs_ + 4);                                 \
    float4v v2 = *(const float4v*)(xs_ + 8);                                 \
    float4v v3 = *(const float4v*)(xs_ + 12);                                \
    ushort8v p0, p1;                                                         \
    _Pragma("unroll") for (int i_ = 0; i_ < 4; ++i_) {                       \
      p0[i_] = f2bf(v0[i_]); p0[4 + i_] = f2bf(v1[i_]);                      \
      p1[i_] = f2bf(v2[i_]); p1[4 + i_] = f2bf(v3[i_]); }                    \
    *(ushort8v*)&sA[buf][arow * 72 + akc] = p0;                              \
    *(ushort8v*)&sA[buf][arow * 72 + akc + 8] = p1; }

  STAGE_B(0, 0)
  STAGE_A(0, 0)
  asm volatile("s_waitcnt vmcnt(0)" ::: "memory");
  __syncthreads();

  float4v acc[2][4];
#pragma unroll
  for (int i = 0; i < 2; ++i)
#pragma unroll
    for (int j = 0; j < 4; ++j) acc[i][j] = (float4v)0.0f;

  for (int step = 0; step < 8; ++step) {
    int p = step & 1;
    if (step < 7) {
      STAGE_B(p ^ 1, (step + 1) * BK)
      STAGE_A(p ^ 1, (step + 1) * BK)
    }
#pragma unroll
    for (int ks = 0; ks < 2; ++ks) {
      short8v a[2], bfr[4];
#pragma unroll
      for (int fm = 0; fm < 2; ++fm) {
        int r = wm * 32 + fm * 16 + (lane & 15);
        int c = ks * 4 + (lane >> 4);
        a[fm] = *(const short8v*)&sA[p][r * 72 + c * 8];
      }
#pragma unroll
      for (int fn = 0; fn < 4; ++fn) {
        int r = wn * 64 + fn * 16 + (lane & 15);
        int c = (ks * 4 + (lane >> 4)) ^ (r & 7);
        bfr[fn] = *(const short8v*)&sB[p][r * BK + c * 8];
      }
#pragma unroll
      for (int fm = 0; fm < 2; ++fm)
#pragma unroll
        for (int fn = 0; fn < 4; ++fn)
          acc[fm][fn] = __builtin_amdgcn_mfma_f32_16x16x32_bf16(a[fm], bfr[fn], acc[fm][fn], 0, 0, 0);
    }
    asm volatile("s_waitcnt vmcnt(0)" ::: "memory");
    __syncthreads();
  }
  // after this barrier no wave reads sB again -> sH/sW2 aliases are safe

  // ---- epilogue-1: +bias, relu, bf16 -> sH [m][n] chunk-swizzled
  float bias[4];
#pragma unroll
  for (int fn = 0; fn < 4; ++fn)
    bias[fn] = bias1[t * DH + n0 + wn * 64 + fn * 16 + (lane & 15)];
#pragma unroll
  for (int fn = 0; fn < 4; ++fn) {
    int n = wn * 64 + fn * 16 + (lane & 15);
#pragma unroll
    for (int fm = 0; fm < 2; ++fm) {
#pragma unroll
      for (int r = 0; r < 4; ++r) {
        int m = wm * 32 + fm * 16 + ((lane >> 4) << 2) + r;
        float v = fmaxf(acc[fm][fn][r] + bias[fn], 0.0f);
        *(short*)((char*)sH + m * 256 + (((n >> 3) ^ (m & 7)) << 4) + ((n & 7) << 1)) =
            (short)f2bf(v);
      }
    }
  }
  // ---- stage W2T slice (32 j x 128 k, chunk-swizzled) into sW2 (aliases sB[1])
#pragma unroll
  for (int it = 0; it < 2; ++it) {
    int ch = it * 256 + tid;
    int j = ch >> 4, c2 = ch & 15;
    ushort8v w = *(const ushort8v*)(W2Tg + ((size_t)t * 32 + j) * DIN + n0 + c2 * 8);
    *(ushort8v*)&sW2[(j * 16 + (c2 ^ (j & 7))) * 8] = w;
  }
  __syncthreads();

  // ---- partial GEMM2: this block's 128-n slice == 128-k slice of layer 2
  float4v acc2[2];
  acc2[0] = (float4v)0.0f; acc2[1] = (float4v)0.0f;
#pragma unroll
  for (int ks = 0; ks < 4; ++ks) {
    int mrow = wave * 16 + (lane & 15);
    int ca = (ks * 4 + (lane >> 4)) ^ (mrow & 7);
    short8v af = *(const short8v*)((char*)sH + mrow * 256 + (ca << 4));
#pragma unroll
    for (int fn = 0; fn < 2; ++fn) {
      int j = fn * 16 + (lane & 15);
      int cb = (ks * 4 + (lane >> 4)) ^ (j & 7);
      short8v bf = *(const short8v*)&sW2[(j * 16 + cb) * 8];
      acc2[fn] = __builtin_amdgcn_mfma_f32_16x16x32_bf16(af, bf, acc2[fn], 0, 0, 0);
    }
  }
#pragma unroll
  for (int fn = 0; fn < 2; ++fn) {
#pragma unroll
    for (int r = 0; r < 4; ++r) {
      int m = wave * 16 + ((lane >> 4) << 2) + r;
      int j = fn * 16 + (lane & 15);
      if (m < mcnt && j < PJ)
        pbuf[((size_t)cs * B_N + row0 + m) * PJ + j] = acc2[fn][r];
    }
  }
#undef STAGE_B
#undef STAGE_A
}

// ============================================================ reduce + softmax
__global__ __launch_bounds__(256) void k_soft(
    const float* __restrict__ pbuf, const float* __restrict__ bias2,
    const int* __restrict__ task_id, const int* __restrict__ action,
    const int* __restrict__ rowidx, float* __restrict__ out) {
  __shared__ float acc[256 * PJ];   // 20 KB
  int tid = threadIdx.x;
  int base = blockIdx.x * 256;
  // coalesced accumulate of 4 partials: 256 rows x 20 floats
#pragma unroll
  for (int it = 0; it < 5; ++it) {
    int idx = it * 256 + tid;            // 0..1279
    int row = idx / 5, j4 = idx - row * 5;
    float4v s = (float4v)0.0f;
#pragma unroll
    for (int c = 0; c < 4; ++c)
      s += *(const float4v*)&pbuf[((size_t)c * B_N + base + row) * PJ + j4 * 4];
    *(float4v*)&acc[row * PJ + j4 * 4] = s;
  }
  __syncthreads();

  int srow = base + tid;
  int orig = rowidx[srow];
  int t = task_id[orig], act = action[orig];
  float lg[NACT];
#pragma unroll
  for (int j = 0; j < NACT; ++j) lg[j] = acc[tid * PJ + j] + bias2[t * NACT + j];
  float mx = lg[0];
#pragma unroll
  for (int j = 1; j < NACT; ++j) mx = fmaxf(mx, lg[j]);
  float s1 = 0.0f, s2 = 0.0f, la = 0.0f;
#pragma unroll
  for (int j = 0; j < NACT; ++j) {
    float e = __expf(lg[j] - mx);
    s1 += e; s2 += e * lg[j];
    la = (j == act) ? lg[j] : la;
  }
  float logZ = __logf(s1);
  float2v o;
  o[0] = la - mx - logZ;
  o[1] = (mx + logZ) - s2 / s1;
  *(float2v*)(out + (size_t)orig * 2) = o;
}

// ----------------------------------------------------------------------------
extern "C" void kernel_launch(void* const* d_in, const int* in_sizes, int n_in,
                              void* d_out, int out_size, void* d_ws, size_t ws_size,
                              hipStream_t stream) {
  const float* x       = (const float*)d_in[0];
  const int*   task_id = (const int*)d_in[1];
  const int*   action  = (const int*)d_in[2];
  const float* W1      = (const float*)d_in[3];
  const float* b1      = (const float*)d_in[4];
  const float* W2      = (const float*)d_in[5];
  const float* b2      = (const float*)d_in[6];
  float* out = (float*)d_out;

  char* ws = (char*)d_ws;
  int* tbl    = (int*)ws;                  // 32 ints: [0:16) cnt, [16:32) offset
  int* rowidx = (int*)(ws + 4096);         // 8192 ints -> ends 36864
  size_t off = 36864;
  short* W1T  = (short*)(ws + off);  off += (size_t)NTASK * DH * DIN * 2;   // 8.39 MB
  short* W2T  = (short*)(ws + off);  off += (size_t)NTASK * 32 * DIN * 2;   // 0.52 MB
  float* pbuf = (float*)(ws + off);                                         // 2.62 MB

  k_prep<<<1153, 256, 0, stream>>>(W1, W2, task_id, W1T, W2T, tbl, rowidx);
  k_gemm1<<<NSLOT + 576, 256, 0, stream>>>(x, b1, W1T, W2T, tbl, rowidx, pbuf);
  k_soft<<<32, 256, 0, stream>>>(pbuf, b2, task_id, action, rowidx, out);
}

// Round 10
// 41.547 us; speedup vs baseline: 2.6721x; 1.0366x over previous
//
#include <hip/hip_runtime.h>
#include <hip/hip_bf16.h>

#define B_N   8192
#define DIN   512
#define DH    512
#define NACT  18
#define NTASK 16
#define BM    64
#define GBN   128
#define BK    64
#define PJ    20      // pbuf row stride (floats)
#define NSLOT 640     // 8 residues x 80 queue slots

typedef __attribute__((ext_vector_type(8))) short  short8v;
typedef __attribute__((ext_vector_type(8))) unsigned short ushort8v;
typedef __attribute__((ext_vector_type(4))) float  float4v;
typedef __attribute__((ext_vector_type(2))) float  float2v;

typedef const __attribute__((address_space(1))) void* gas_ptr;
typedef __attribute__((address_space(3))) void* las_ptr;

__device__ __forceinline__ unsigned short f2bf(float f) {
  union { float f; unsigned int u; } c; c.f = f;
  unsigned int u = c.u;
  u += 0x7fffu + ((u >> 16) & 1u);   // RNE
  return (unsigned short)(u >> 16);
}

// ============================================================ prep kernel
// block 0          : histogram + 16-entry prefix + parallel scatter
// blocks 1..1024   : W1 [t][k][n] f32 -> W1T [t][n][k] bf16 (XCD-aligned producer)
// blocks 1025..1152: W2 [t][k][18] f32 -> W2T [t][32pad][512] bf16
__global__ __launch_bounds__(256) void k_prep(
    const float* __restrict__ W1, const float* __restrict__ W2,
    const int* __restrict__ task_id,
    short* __restrict__ W1T, short* __restrict__ W2T,
    int* __restrict__ tbl, int* __restrict__ rowidx) {
  __shared__ __align__(16) short ldsA[64][72];
  __shared__ float ldsB[64 * 19];
  __shared__ int s_cnt[NTASK], s_cur[NTASK];
  int bx = blockIdx.x, tid = threadIdx.x;

  if (bx == 0) {
    if (tid < NTASK) s_cnt[tid] = 0;
    __syncthreads();
    for (int i = tid; i < B_N; i += 256) atomicAdd(&s_cnt[task_id[i]], 1);
    __syncthreads();
    if (tid == 0) {                       // 16 iterations only
      int acc = 0;
#pragma unroll
      for (int t = 0; t < NTASK; ++t) {
        int c = s_cnt[t];
        tbl[t] = c; tbl[16 + t] = acc; s_cur[t] = acc;
        acc += c;
      }
    }
    __syncthreads();
    for (int i = tid; i < B_N; i += 256) {
      int t = task_id[i];
      rowidx[atomicAdd(&s_cur[t], 1)] = i;
    }
  } else if (bx <= 1024) {
    int r = bx & 7;
    int q = ((bx - r) >> 3) - (r == 0 ? 1 : 0);   // 0..127
    int t = r + ((q >> 6) << 3);                  // tasks {r, r+8}
    int sub = q & 63;
    int kb = sub >> 3, nb = sub & 7;
    int kr = tid >> 2, c16 = (tid & 3) << 4;
    const float* src = W1 + ((size_t)t * DIN + (size_t)(kb * 64 + kr)) * DH + nb * 64 + c16;
#pragma unroll
    for (int p = 0; p < 4; ++p) {
      float4v v = *(const float4v*)(src + p * 4);
#pragma unroll
      for (int i = 0; i < 4; ++i) ldsA[c16 + p * 4 + i][kr] = (short)f2bf(v[i]);
    }
    __syncthreads();
    int n = tid >> 2, k16 = (tid & 3) << 4;
    short* dst = W1T + ((size_t)t * DH + nb * 64 + n) * DIN + kb * 64 + k16;
    *(ushort8v*)dst       = *(ushort8v*)&ldsA[n][k16];
    *(ushort8v*)(dst + 8) = *(ushort8v*)&ldsA[n][k16 + 8];
  } else {
    int u = bx - 1025;
    int t = u >> 3, k0 = (u & 7) * 64;
    for (int i = tid; i < 64 * NACT; i += 256) {
      int kk = i / NACT, j = i - kk * NACT;
      ldsB[kk * 19 + j] = W2[((size_t)t * DIN + k0 + kk) * NACT + j];
    }
    __syncthreads();
    for (int o = tid; o < 32 * 64; o += 256) {
      int j = o >> 6, kk = o & 63;
      float val = (j < NACT) ? ldsB[kk * 19 + j] : 0.0f;
      W2T[((size_t)t * 32 + j) * DIN + k0 + kk] = (short)f2bf(val);
    }
  }
}

// ============================================================ grouped GEMM1 + partial GEMM2
// R9 structure; K-loop unrolled (static buffer index) + T14 split A-staging:
// issue x loads early, cvt+ds_write AFTER the MFMA cluster.
__global__ __launch_bounds__(256, 3) void k_gemm1(
    const float* __restrict__ x, const float* __restrict__ bias1,
    const short* __restrict__ W1T, const short* __restrict__ W2Tg,
    const int* __restrict__ tbl, const int* __restrict__ rowidx,
    float* __restrict__ pbuf) {
  __shared__ __align__(16) short sA[2][BM * 72];    // 2 x 9 KB (padded, reg-staged)
  __shared__ __align__(16) short sB[2][GBN * BK];   // 2 x 16 KB (gload_lds, XOR-swz)
  short* sH  = sB[0];   // 16 KB, used only after the K-loop
  short* sW2 = sB[1];   // 8 KB,  used only after the K-loop
  __shared__ int s_rows[64];
  int tid = threadIdx.x, lane = tid & 63, wave = tid >> 6;

  // ---- decode (verified R5): residue b&7 serves tasks {r, r+8}
  int b = blockIdx.x;
  int t = -1, rel = 0;
  if (b < NSLOT) {
    int r = b & 7, q = b >> 3;
    int n0t = (tbl[r] + 63) >> 6, n1t = (tbl[r + 8] + 63) >> 6;
    if (q < 4 * n0t) { t = r; rel = q; }
    else if (q < 4 * (n0t + n1t)) { t = r + 8; rel = q - 4 * n0t; }
    else return;
  } else {
    int j = b - NSLOT;
    for (int r = 0; r < 8; ++r) {
      int n0t = (tbl[r] + 63) >> 6, n1t = (tbl[r + 8] + 63) >> 6;
      int P = 4 * (n0t + n1t);
      int S = (P > 80) ? (P - 80) : 0;
      if (j < S) {
        int q = 80 + j;
        if (q < 4 * n0t) { t = r; rel = q; }
        else { t = r + 8; rel = q - 4 * n0t; }
        break;
      }
      j -= S;
    }
    if (t < 0) return;
  }
  int itile = rel >> 2, cs = rel & 3;
  int cnt_t = tbl[t], off_t = tbl[16 + t];
  int row0 = off_t + itile * 64;
  int mcnt = cnt_t - itile * 64; if (mcnt > 64) mcnt = 64;
  int n0 = cs * GBN;
  int wm = wave >> 1, wn = wave & 1;

  if (tid < 64) {
    int idx = row0 + tid;
    if (idx > B_N - 1) idx = B_N - 1;
    s_rows[tid] = rowidx[idx];
  }
  __syncthreads();

  // ---- staging setup
  int arow = tid >> 2, akc = (tid & 3) << 4;       // A: 4 thr/row, 16 k each
  const float* xrow = x + (size_t)s_rows[arow] * DIN + akc;
  const short* Bbase = W1T + ((size_t)t * DH + n0) * DIN;

  float4v La0, La1, La2, La3;
#define LOAD_A(k0e) {                                                        \
    const float* xs_ = xrow + (k0e);                                         \
    La0 = *(const float4v*)xs_;                                              \
    La1 = *(const float4v*)(xs_ + 4);                                        \
    La2 = *(const float4v*)(xs_ + 8);                                        \
    La3 = *(const float4v*)(xs_ + 12); }
#define WRITE_A(buf) {                                                       \
    ushort8v p0, p1;                                                         \
    _Pragma("unroll") for (int i_ = 0; i_ < 4; ++i_) {                       \
      p0[i_] = f2bf(La0[i_]); p0[4 + i_] = f2bf(La1[i_]);                    \
      p1[i_] = f2bf(La2[i_]); p1[4 + i_] = f2bf(La3[i_]); }                  \
    *(ushort8v*)&sA[buf][arow * 72 + akc] = p0;                              \
    *(ushort8v*)&sA[buf][arow * 72 + akc + 8] = p1; }
#define STAGE_B(buf, k0e)                                                    \
  _Pragma("unroll") for (int it = 0; it < 4; ++it) {                         \
    int ch = it * 256 + tid; int row = ch >> 3, cc = ch & 7;                 \
    int sc = cc ^ (row & 7);                                                 \
    __builtin_amdgcn_global_load_lds(                                        \
        (gas_ptr)(const void*)(Bbase + (size_t)row * DIN + (k0e) + sc * 8),  \
        (las_ptr)(void*)(&sB[buf][ch * 8]), 16, 0, 0);                       \
  }

  // prologue
  LOAD_A(0)
  STAGE_B(0, 0)
  WRITE_A(0)                               // cvt auto-waits the A loads
  asm volatile("s_waitcnt vmcnt(0)" ::: "memory");
  __syncthreads();

  float4v acc[2][4];
#pragma unroll
  for (int i = 0; i < 2; ++i)
#pragma unroll
    for (int j = 0; j < 4; ++j) acc[i][j] = (float4v)0.0f;

#pragma unroll
  for (int step = 0; step < 8; ++step) {
    const int p = step & 1;
    if (step < 7) {
      LOAD_A((step + 1) * BK)              // issue x loads early (regs)
      STAGE_B(p ^ 1, (step + 1) * BK)      // issue B gload_lds
    }
#pragma unroll
    for (int ks = 0; ks < 2; ++ks) {
      short8v a[2], bfr[4];
#pragma unroll
      for (int fm = 0; fm < 2; ++fm) {
        int r = wm * 32 + fm * 16 + (lane & 15);
        int c = ks * 4 + (lane >> 4);
        a[fm] = *(const short8v*)&sA[p][r * 72 + c * 8];
      }
#pragma unroll
      for (int fn = 0; fn < 4; ++fn) {
        int r = wn * 64 + fn * 16 + (lane & 15);
        int c = (ks * 4 + (lane >> 4)) ^ (r & 7);
        bfr[fn] = *(const short8v*)&sB[p][r * BK + c * 8];
      }
#pragma unroll
      for (int fm = 0; fm < 2; ++fm)
#pragma unroll
        for (int fn = 0; fn < 4; ++fn)
          acc[fm][fn] = __builtin_amdgcn_mfma_f32_16x16x32_bf16(a[fm], bfr[fn], acc[fm][fn], 0, 0, 0);
    }
    if (step < 7) {
      WRITE_A(p ^ 1)                       // cvt+ds_write AFTER MFMAs (T14 write-late)
    }
    asm volatile("s_waitcnt vmcnt(0)" ::: "memory");
    __syncthreads();
  }
  // after this barrier no wave reads sB again -> sH/sW2 aliases are safe

  // ---- epilogue-1: +bias, relu, bf16 -> sH [m][n] chunk-swizzled
  float bias[4];
#pragma unroll
  for (int fn = 0; fn < 4; ++fn)
    bias[fn] = bias1[t * DH + n0 + wn * 64 + fn * 16 + (lane & 15)];
#pragma unroll
  for (int fn = 0; fn < 4; ++fn) {
    int n = wn * 64 + fn * 16 + (lane & 15);
#pragma unroll
    for (int fm = 0; fm < 2; ++fm) {
#pragma unroll
      for (int r = 0; r < 4; ++r) {
        int m = wm * 32 + fm * 16 + ((lane >> 4) << 2) + r;
        float v = fmaxf(acc[fm][fn][r] + bias[fn], 0.0f);
        *(short*)((char*)sH + m * 256 + (((n >> 3) ^ (m & 7)) << 4) + ((n & 7) << 1)) =
            (short)f2bf(v);
      }
    }
  }
  // ---- stage W2T slice (32 j x 128 k, chunk-swizzled) into sW2 (aliases sB[1])
#pragma unroll
  for (int it = 0; it < 2; ++it) {
    int ch = it * 256 + tid;
    int j = ch >> 4, c2 = ch & 15;
    ushort8v w = *(const ushort8v*)(W2Tg + ((size_t)t * 32 + j) * DIN + n0 + c2 * 8);
    *(ushort8v*)&sW2[(j * 16 + (c2 ^ (j & 7))) * 8] = w;
  }
  __syncthreads();

  // ---- partial GEMM2: this block's 128-n slice == 128-k slice of layer 2
  float4v acc2[2];
  acc2[0] = (float4v)0.0f; acc2[1] = (float4v)0.0f;
#pragma unroll
  for (int ks = 0; ks < 4; ++ks) {
    int mrow = wave * 16 + (lane & 15);
    int ca = (ks * 4 + (lane >> 4)) ^ (mrow & 7);
    short8v af = *(const short8v*)((char*)sH + mrow * 256 + (ca << 4));
#pragma unroll
    for (int fn = 0; fn < 2; ++fn) {
      int j = fn * 16 + (lane & 15);
      int cb = (ks * 4 + (lane >> 4)) ^ (j & 7);
      short8v bf = *(const short8v*)&sW2[(j * 16 + cb) * 8];
      acc2[fn] = __builtin_amdgcn_mfma_f32_16x16x32_bf16(af, bf, acc2[fn], 0, 0, 0);
    }
  }
#pragma unroll
  for (int fn = 0; fn < 2; ++fn) {
#pragma unroll
    for (int r = 0; r < 4; ++r) {
      int m = wave * 16 + ((lane >> 4) << 2) + r;
      int j = fn * 16 + (lane & 15);
      if (m < mcnt && j < PJ)
        pbuf[((size_t)cs * B_N + row0 + m) * PJ + j] = acc2[fn][r];
    }
  }
#undef STAGE_B
#undef LOAD_A
#undef WRITE_A
}

// ============================================================ reduce + softmax
__global__ __launch_bounds__(256) void k_soft(
    const float* __restrict__ pbuf, const float* __restrict__ bias2,
    const int* __restrict__ task_id, const int* __restrict__ action,
    const int* __restrict__ rowidx, float* __restrict__ out) {
  __shared__ float acc[256 * PJ];   // 20 KB
  int tid = threadIdx.x;
  int base = blockIdx.x * 256;
#pragma unroll
  for (int it = 0; it < 5; ++it) {
    int idx = it * 256 + tid;            // 0..1279
    int row = idx / 5, j4 = idx - row * 5;
    float4v s = (float4v)0.0f;
#pragma unroll
    for (int c = 0; c < 4; ++c)
      s += *(const float4v*)&pbuf[((size_t)c * B_N + base + row) * PJ + j4 * 4];
    *(float4v*)&acc[row * PJ + j4 * 4] = s;
  }
  __syncthreads();

  int srow = base + tid;
  int orig = rowidx[srow];
  int t = task_id[orig], act = action[orig];
  float lg[NACT];
#pragma unroll
  for (int j = 0; j < NACT; ++j) lg[j] = acc[tid * PJ + j] + bias2[t * NACT + j];
  float mx = lg[0];
#pragma unroll
  for (int j = 1; j < NACT; ++j) mx = fmaxf(mx, lg[j]);
  float s1 = 0.0f, s2 = 0.0f, la = 0.0f;
#pragma unroll
  for (int j = 0; j < NACT; ++j) {
    float e = __expf(lg[j] - mx);
    s1 += e; s2 += e * lg[j];
    la = (j == act) ? lg[j] : la;
  }
  float logZ = __logf(s1);
  float2v o;
  o[0] = la - mx - logZ;
  o[1] = (mx + logZ) - s2 / s1;
  *(float2v*)(out + (size_t)orig * 2) = o;
}

// ----------------------------------------------------------------------------
extern "C" void kernel_launch(void* const* d_in, const int* in_sizes, int n_in,
                              void* d_out, int out_size, void* d_ws, size_t ws_size,
                              hipStream_t stream) {
  const float* x       = (const float*)d_in[0];
  const int*   task_id = (const int*)d_in[1];
  const int*   action  = (const int*)d_in[2];
  const float* W1      = (const float*)d_in[3];
  const float* b1      = (const float*)d_in[4];
  const float* W2      = (const float*)d_in[5];
  const float* b2      = (const float*)d_in[6];
  float* out = (float*)d_out;

  char* ws = (char*)d_ws;
  int* tbl    = (int*)ws;                  // 32 ints: [0:16) cnt, [16:32) offset
  int* rowidx = (int*)(ws + 4096);         // 8192 ints -> ends 36864
  size_t off = 36864;
  short* W1T  = (short*)(ws + off);  off += (size_t)NTASK * DH * DIN * 2;   // 8.39 MB
  short* W2T  = (short*)(ws + off);  off += (size_t)NTASK * 32 * DIN * 2;   // 0.52 MB
  float* pbuf = (float*)(ws + off);                                         // 2.62 MB

  k_prep<<<1153, 256, 0, stream>>>(W1, W2, task_id, W1T, W2T, tbl, rowidx);
  k_gemm1<<<NSLOT + 576, 256, 0, stream>>>(x, b1, W1T, W2T, tbl, rowidx, pbuf);
  k_soft<<<32, 256, 0, stream>>>(pbuf, b2, task_id, action, rowidx, out);
}